// Round 19
// baseline (85.820 us; speedup 1.0000x reference)
//
#include <hip/hip_runtime.h>
#include <cmath>
#include <cstdint>

#define NB 32
#define NP 24564
#define NC 81
#define NEG_POS 3

static constexpr size_t MINED_ELEMS = (size_t)NB * NP;             // 786,048
static constexpr size_t MINED_BYTES = MINED_ELEMS * sizeof(float); // 3,144,192

#define NTILES8 ((int)(MINED_ELEMS / 8))   // 98,256 = 8188 * 12 exactly
#define MAIN_BLOCKS 2047                   // 4 waves each -> 8188 waves
#define TOTAL_WAVES (MAIN_BLOCKS * 4)
#define KITERS 6                           // x2 bodies = 12 tiles per wave

// ws layout:
//   [0, MINED_BYTES)            float mined[NB*NP] (sign bit = positive row, |v| = ce)
//   [MINED_BYTES, +512)         float partial[NB][4] {loc, ce_pos, neg_sum, pad}
//   [MINED_BYTES+512, +4*NB)    int   num_pos[NB]

__device__ __forceinline__ float wave_reduce_sum(float v) {
#pragma unroll
  for (int off = 32; off > 0; off >>= 1) v += __shfl_down(v, off, 64);
  return v;
}

__device__ __forceinline__ float smooth_l1_4(float4 a, float4 t) {
  float acc = 0.f, d, ax;
  d = a.x - t.x; ax = fabsf(d); acc += (ax < 1.f) ? 0.5f * d * d : ax - 0.5f;
  d = a.y - t.y; ax = fabsf(d); acc += (ax < 1.f) ? 0.5f * d * d : ax - 0.5f;
  d = a.z - t.z; ax = fabsf(d); acc += (ax < 1.f) ? 0.5f * d * d : ax - 0.5f;
  d = a.w - t.w; ax = fabsf(d); acc += (ax < 1.f) ? 0.5f * d * d : ax - 0.5f;
  return acc;
}

// Branch-free CE kernel: 8-row tiles (12 iters/wave), depth-2 data prefetch,
// targets via readfirstlane-uniform scalar loads (off the vmcnt queue, no
// VGPR cost), 2-deep target ping-pong. Per row: 0.625 VMEM ops, ~2.1 DS ops.
__global__ __launch_bounds__(256, 8) void mb_main(
    const float* __restrict__ conf_data, const int* __restrict__ conf_targets,
    float* __restrict__ mined) {
  __shared__ float lds[4][656];   // 648 data + dump slot @648 (16B aligned)

  const int tid  = (int)threadIdx.x;
  const int wid  = tid >> 6, lane = tid & 63;
  const int r    = lane >> 3, il = lane & 7;   // 8 rows x 8 lanes
  float* __restrict__ L = lds[wid];

  const int src3  = 128 + ((lane < 34) ? lane : 33);          // clamped 3rd src
  const int ldst3 = (lane < 34) ? (4 * (128 + lane)) : 648;   // dump for lanes>=34

#define LOAD_DATA(c0, c1, c2, t)                                        \
  do {                                                                  \
    const float4* __restrict__ _s =                                     \
        reinterpret_cast<const float4*>(conf_data) + (size_t)(t) * 162; \
    (c0) = _s[lane];                                                    \
    (c1) = _s[64 + lane];                                               \
    (c2) = _s[src3];                                                    \
  } while (0)

#define LOAD_TG(ta, tb, t)                                                   \
  do {                                                                       \
    const int _ut = __builtin_amdgcn_readfirstlane(t);                       \
    (ta) = *reinterpret_cast<const int4*>(conf_targets + (size_t)_ut * 8);   \
    (tb) = *reinterpret_cast<const int4*>(conf_targets + (size_t)_ut * 8 + 4); \
  } while (0)

#define STAGE(c0, c1, c2)                                   \
  do {                                                      \
    *reinterpret_cast<float4*>(&L[4 * lane]) = (c0);        \
    *reinterpret_cast<float4*>(&L[4 * (64 + lane)]) = (c1); \
    *reinterpret_cast<float4*>(&L[ldst3]) = (c2);           \
  } while (0)

#define COMPUTE(t, ta, tb)                                              \
  do {                                                                  \
    const int tgt = (r < 4)                                             \
        ? ((r == 0) ? (ta).x : (r == 1) ? (ta).y                        \
           : (r == 2) ? (ta).z : (ta).w)                                \
        : ((r == 4) ? (tb).x : (r == 5) ? (tb).y                        \
           : (r == 6) ? (tb).z : (tb).w);                               \
    const int rb = 81 * r;                                              \
    float e = __expf(L[rb + il])      + __expf(L[rb + il + 8]) +        \
              __expf(L[rb + il + 16]) + __expf(L[rb + il + 24]) +       \
              __expf(L[rb + il + 32]) + __expf(L[rb + il + 40]) +       \
              __expf(L[rb + il + 48]) + __expf(L[rb + il + 56]) +       \
              __expf(L[rb + il + 64]) + __expf(L[rb + il + 72]);        \
    if (il == 0) e += __expf(L[rb + 80]);                               \
    e += __shfl_xor(e, 1, 64);                                          \
    e += __shfl_xor(e, 2, 64);                                          \
    e += __shfl_xor(e, 4, 64);                                          \
    const float tv = L[rb + tgt];                                       \
    const float ce = __logf(e) - tv;                                    \
    const float val = (tgt > 0) ? -ce : ce;                             \
    if (il == 0) mined[(t) * 8 + r] = val;                              \
  } while (0)

  int tile = (int)blockIdx.x * 4 + wid;
  float4 cA0, cA1, cA2, cB0, cB1, cB2;
  int4 taA, tbA, taB, tbB, taN, tbN;

  LOAD_DATA(cA0, cA1, cA2, tile);
  LOAD_TG(taA, tbA, tile);
  {
    const int tB = tile + TOTAL_WAVES;   // always < NTILES8 (8188*12 layout)
    LOAD_DATA(cB0, cB1, cB2, tB);
    LOAD_TG(taB, tbB, tB);
  }

#pragma unroll 1
  for (int k = 0; k < KITERS; ++k) {
    // ---- body A ----
    STAGE(cA0, cA1, cA2);                 // waits on cA loads from 2 iters ago
    {
      int nt = tile + 2 * TOTAL_WAVES;
      nt = (nt < NTILES8) ? nt : tile;
      LOAD_DATA(cA0, cA1, cA2, nt);
      LOAD_TG(taN, tbN, nt);
    }
    __builtin_amdgcn_sched_barrier(0);    // keep prefetch above compute
    COMPUTE(tile, taA, tbA);
    taA = taB; tbA = tbB; taB = taN; tbB = tbN;
    tile += TOTAL_WAVES;

    // ---- body B ----
    STAGE(cB0, cB1, cB2);
    {
      int nt = tile + 2 * TOTAL_WAVES;
      nt = (nt < NTILES8) ? nt : tile;
      LOAD_DATA(cB0, cB1, cB2, nt);
      LOAD_TG(taN, tbN, nt);
    }
    __builtin_amdgcn_sched_barrier(0);
    COMPUTE(tile, taA, tbA);
    taA = taB; tbA = tbB; taB = taN; tbB = tbN;
    tile += TOTAL_WAVES;
  }
#undef LOAD_DATA
#undef LOAD_TG
#undef STAGE
#undef COMPUTE
}

// One block per batch row (R18, unchanged): fused positives+top-byte sweep,
// then 3 radix sweeps, then strictly-greater sum sweep.
__global__ __launch_bounds__(1024) void mb_select(
    const float* __restrict__ mined, const float* __restrict__ loc_data,
    const float* __restrict__ loc_targets, float* __restrict__ partial,
    int* __restrict__ num_pos) {
  const int b = blockIdx.x;
  const float* __restrict__ row = mined + (size_t)b * NP;
  const int tid = threadIdx.x;
  const int wid = tid >> 6;
  const int lane = tid & 63;

  __shared__ int hist[16][256];
  __shared__ int total[256];
  __shared__ int suffix[256];
  __shared__ unsigned s_prefix;
  __shared__ int s_k;

  // ---- sweep 1: fused positives pre-pass + top-byte histogram ----
  for (int i = tid; i < 16 * 256; i += 1024) ((int*)hist)[i] = 0;
  __syncthreads();
  {
    int np = 0;
    float cp = 0.f, lv = 0.f;
    for (int q = tid; q < NP / 4; q += 1024) {
      const float4 v = reinterpret_cast<const float4*>(row)[q];
      const float vv[4] = {v.x, v.y, v.z, v.w};
#pragma unroll
      for (int j = 0; j < 4; ++j) {
        unsigned u = __float_as_uint(vv[j]);
        if (u >> 31) {
          np++;
          cp += -vv[j];
          const size_t flat = (size_t)b * NP + 4 * q + j;
          lv += smooth_l1_4(
              *reinterpret_cast<const float4*>(loc_data + flat * 4),
              *reinterpret_cast<const float4*>(loc_targets + flat * 4));
          u = 0u;
        }
        atomicAdd(&hist[wid][u >> 24], 1);
      }
    }
    __shared__ float rednp[16], redcp[16], redlv[16];
    float wnp = wave_reduce_sum((float)np);
    float wcp = wave_reduce_sum(cp);
    float wlv = wave_reduce_sum(lv);
    if (lane == 0) { rednp[wid] = wnp; redcp[wid] = wcp; redlv[wid] = wlv; }
    __syncthreads();
    if (tid == 0) {
      float tnp = 0.f, tcp = 0.f, tlv = 0.f;
#pragma unroll
      for (int i = 0; i < 16; ++i) { tnp += rednp[i]; tcp += redcp[i]; tlv += redlv[i]; }
      const int npi = (int)tnp;
      num_pos[b] = npi;
      partial[b * 4 + 0] = tlv;
      partial[b * 4 + 1] = tcp;
      int k = NEG_POS * npi;
      if (k > NP - 1) k = NP - 1;
      s_k = k;
      s_prefix = 0u;
    }
    __syncthreads();
  }

#define PASS_EPILOGUE(SHIFT)                                                  \
  do {                                                                        \
    if (tid < 256) {                                                          \
      int t = 0;                                                              \
      _Pragma("unroll")                                                       \
      for (int w = 0; w < 16; ++w) t += hist[w][tid];                         \
      total[tid] = t;                                                         \
    }                                                                         \
    __syncthreads();                                                          \
    if (wid == 0) {                                                           \
      const int t0_ = total[4 * lane + 0];                                    \
      const int t1_ = total[4 * lane + 1];                                    \
      const int t2_ = total[4 * lane + 2];                                    \
      const int t3_ = total[4 * lane + 3];                                    \
      const int s3 = t3_;                                                     \
      const int s2 = t2_ + s3;                                                \
      const int s1 = t1_ + s2;                                                \
      const int s0 = t0_ + s1;                                                \
      int acc_ = s0;                                                          \
      _Pragma("unroll")                                                       \
      for (int off = 1; off < 64; off <<= 1) {                                \
        const int o = __shfl_down(acc_, off, 64);                             \
        if (lane + off < 64) acc_ += o;                                       \
      }                                                                       \
      const int excl = acc_ - s0;                                             \
      suffix[4 * lane + 0] = s0 + excl;                                       \
      suffix[4 * lane + 1] = s1 + excl;                                       \
      suffix[4 * lane + 2] = s2 + excl;                                       \
      suffix[4 * lane + 3] = s3 + excl;                                       \
    }                                                                         \
    __syncthreads();                                                          \
    if (tid < 256) {                                                          \
      const int kcur = s_k;                                                   \
      const int cs = suffix[tid] - total[tid];                                \
      if (kcur >= cs && kcur < cs + total[tid]) {                             \
        s_prefix |= ((unsigned)tid << (SHIFT));                               \
        s_k = kcur - cs;                                                      \
      }                                                                       \
    }                                                                         \
    __syncthreads();                                                          \
  } while (0)

  PASS_EPILOGUE(24);

  for (int shift = 16; shift >= 0; shift -= 8) {
    for (int i = tid; i < 16 * 256; i += 1024) ((int*)hist)[i] = 0;
    __syncthreads();
    const unsigned mask = 0xFFFFFFFFu << (shift + 8);
    const unsigned pfx = s_prefix;

    for (int q = tid; q < NP / 4; q += 1024) {
      const float4 v = reinterpret_cast<const float4*>(row)[q];
      unsigned u;
      u = __float_as_uint(v.x); u = (u >> 31) ? 0u : u; if ((u & mask) == pfx) atomicAdd(&hist[wid][(u >> shift) & 255], 1);
      u = __float_as_uint(v.y); u = (u >> 31) ? 0u : u; if ((u & mask) == pfx) atomicAdd(&hist[wid][(u >> shift) & 255], 1);
      u = __float_as_uint(v.z); u = (u >> 31) ? 0u : u; if ((u & mask) == pfx) atomicAdd(&hist[wid][(u >> shift) & 255], 1);
      u = __float_as_uint(v.w); u = (u >> 31) ? 0u : u; if ((u & mask) == pfx) atomicAdd(&hist[wid][(u >> shift) & 255], 1);
    }
    __syncthreads();

    if (shift == 16) PASS_EPILOGUE(16);
    else if (shift == 8) PASS_EPILOGUE(8);
    else PASS_EPILOGUE(0);
  }
#undef PASS_EPILOGUE

  const unsigned vbits = s_prefix;
  float sum = 0.f;
  for (int q = tid; q < NP / 4; q += 1024) {
    const float4 v = reinterpret_cast<const float4*>(row)[q];
    unsigned u;
    u = __float_as_uint(v.x); u = (u >> 31) ? 0u : u; if (u > vbits) sum += v.x;
    u = __float_as_uint(v.y); u = (u >> 31) ? 0u : u; if (u > vbits) sum += v.y;
    u = __float_as_uint(v.z); u = (u >> 31) ? 0u : u; if (u > vbits) sum += v.z;
    u = __float_as_uint(v.w); u = (u >> 31) ? 0u : u; if (u > vbits) sum += v.w;
  }

  __shared__ float wsum[16];
  float w = wave_reduce_sum(sum);
  if (lane == 0) wsum[wid] = w;
  __syncthreads();
  if (tid == 0) {
    float t = 0.f;
#pragma unroll
    for (int i = 0; i < 16; ++i) t += wsum[i];
    partial[b * 4 + 2] = t;
  }
}

__global__ void mb_finalize(const float* __restrict__ partial,
                            const int* __restrict__ num_pos,
                            float* __restrict__ out) {
  if (threadIdx.x == 0) {
    double s = 0.0;
    int tot = 0;
#pragma unroll
    for (int i = 0; i < NB; ++i) {
      s += (double)partial[i * 4 + 0] + (double)partial[i * 4 + 1] +
           (double)partial[i * 4 + 2];
      tot += num_pos[i];
    }
    const double n = (double)(tot > 0 ? tot : 1);
    out[0] = (float)(s / n);
  }
}

extern "C" void kernel_launch(void* const* d_in, const int* in_sizes, int n_in,
                              void* d_out, int out_size, void* d_ws, size_t ws_size,
                              hipStream_t stream) {
  const float* loc_data     = (const float*)d_in[0];
  const float* conf_data    = (const float*)d_in[1];
  const float* loc_targets  = (const float*)d_in[2];
  const int*   conf_targets = (const int*)d_in[3];
  float* out = (float*)d_out;

  float* mined   = (float*)d_ws;
  float* partial = (float*)((char*)d_ws + MINED_BYTES);
  int*   num_pos = (int*)((char*)d_ws + MINED_BYTES + 512);

  mb_main<<<MAIN_BLOCKS, 256, 0, stream>>>(conf_data, conf_targets, mined);

  mb_select<<<NB, 1024, 0, stream>>>(mined, loc_data, loc_targets, partial, num_pos);

  mb_finalize<<<1, 64, 0, stream>>>(partial, num_pos, out);
}

// Round 20
// 85.494 us; speedup vs baseline: 1.0038x; 1.0038x over previous
//
#include <hip/hip_runtime.h>
#include <cmath>
#include <cstdint>

#define NB 32
#define NP 24564
#define NC 81
#define NEG_POS 3

static constexpr size_t MINED_ELEMS = (size_t)NB * NP;             // 786,048
static constexpr size_t MINED_BYTES = MINED_ELEMS * sizeof(float); // 3,144,192

#define NTILES4 ((int)(MINED_ELEMS / 4))   // 196,512 = 8188 * 24 exactly
#define MAIN_BLOCKS 2047                   // 4 waves each -> 8188 waves
#define TOTAL_WAVES (MAIN_BLOCKS * 4)
#define KITERS 12                          // x2 bodies = 24 tiles per wave

// ws layout:
//   [0, MINED_BYTES)            float mined[NB*NP] (sign bit = positive row, |v| = ce)
//   [MINED_BYTES, +512)         float partial[NB][4] {loc, ce_pos, neg_sum, pad}
//   [MINED_BYTES+512, +4*NB)    int   num_pos[NB]

__device__ __forceinline__ float wave_reduce_sum(float v) {
#pragma unroll
  for (int off = 32; off > 0; off >>= 1) v += __shfl_down(v, off, 64);
  return v;
}

__device__ __forceinline__ float smooth_l1_4(float4 a, float4 t) {
  float acc = 0.f, d, ax;
  d = a.x - t.x; ax = fabsf(d); acc += (ax < 1.f) ? 0.5f * d * d : ax - 0.5f;
  d = a.y - t.y; ax = fabsf(d); acc += (ax < 1.f) ? 0.5f * d * d : ax - 0.5f;
  d = a.z - t.z; ax = fabsf(d); acc += (ax < 1.f) ? 0.5f * d * d : ax - 0.5f;
  d = a.w - t.w; ax = fabsf(d); acc += (ax < 1.f) ? 0.5f * d * d : ax - 0.5f;
  return acc;
}

// Branch-free CE kernel: depth-2 pipeline (STAGE waits on loads issued two
// iterations ago; rolling nonzero vmcnt), targets rotate 3-deep so COMPUTE
// never waits on anything issued this iteration. No conditional VMEM.
__global__ __launch_bounds__(256, 8) void mb_main(
    const float* __restrict__ conf_data, const int* __restrict__ conf_targets,
    float* __restrict__ mined) {
  __shared__ float lds[4][332];   // 324 data + dump slot

  const int tid  = (int)threadIdx.x;
  const int wid  = tid >> 6, lane = tid & 63;
  const int r    = lane >> 4, il = lane & 15;
  float* __restrict__ L = lds[wid];

  const int l17   = (lane < 17) ? lane : 16;              // clamped src index
  const int ldst1 = (lane < 17) ? (256 + 4 * l17) : 328;  // dump for lanes>=17

#define LOAD_DATA(c0, c1, t)                                            \
  do {                                                                  \
    const float4* __restrict__ _s =                                     \
        reinterpret_cast<const float4*>(conf_data) + (size_t)(t) * 81;  \
    (c0) = _s[lane];                                                    \
    (c1) = _s[64 + l17];                                                \
  } while (0)

#define STAGE(c0, c1)                                  \
  do {                                                 \
    *reinterpret_cast<float4*>(&L[4 * lane]) = (c0);   \
    *reinterpret_cast<float4*>(&L[ldst1]) = (c1);      \
  } while (0)

#define COMPUTE(t, tg)                                                  \
  do {                                                                  \
    const int tgt = (r == 0) ? (tg).x : (r == 1) ? (tg).y               \
                  : (r == 2) ? (tg).z : (tg).w;                         \
    const int rb = 81 * r;                                              \
    float e = __expf(L[rb + il]) + __expf(L[rb + il + 16]) +            \
              __expf(L[rb + il + 32]) + __expf(L[rb + il + 48]) +       \
              __expf(L[rb + il + 64]);                                  \
    if (il == 0) e += __expf(L[rb + 80]);                               \
    e += __shfl_xor(e, 1, 64);                                          \
    e += __shfl_xor(e, 2, 64);                                          \
    e += __shfl_xor(e, 4, 64);                                          \
    e += __shfl_xor(e, 8, 64);                                          \
    const float tv = L[rb + tgt];                                       \
    const float ce = __logf(e) - tv;                                    \
    const float val = (tgt > 0) ? -ce : ce;                             \
    mined[(t) * 4 + r] = val;                                           \
  } while (0)

  int tile = (int)blockIdx.x * 4 + wid;
  float4 cA0, cA1, cB0, cB1;
  int4 tg0, tg1, tgN;

  LOAD_DATA(cA0, cA1, tile);
  tg0 = *reinterpret_cast<const int4*>(conf_targets + (size_t)tile * 4);
  {
    const int tB = tile + TOTAL_WAVES;   // always < NTILES4 (8188*24 layout)
    LOAD_DATA(cB0, cB1, tB);
    tg1 = *reinterpret_cast<const int4*>(conf_targets + (size_t)tB * 4);
  }

#pragma unroll 1
  for (int k = 0; k < KITERS; ++k) {
    // ---- body A ----
    STAGE(cA0, cA1);                      // waits on cA loads from 2 iters ago
    {
      int nt = tile + 2 * TOTAL_WAVES;
      nt = (nt < NTILES4) ? nt : tile;
      LOAD_DATA(cA0, cA1, nt);
      tgN = *reinterpret_cast<const int4*>(conf_targets + (size_t)nt * 4);
    }
    __builtin_amdgcn_sched_barrier(0);    // keep prefetch above compute
    COMPUTE(tile, tg0);
    tg0 = tg1; tg1 = tgN;
    tile += TOTAL_WAVES;

    // ---- body B ----
    STAGE(cB0, cB1);
    {
      int nt = tile + 2 * TOTAL_WAVES;
      nt = (nt < NTILES4) ? nt : tile;
      LOAD_DATA(cB0, cB1, nt);
      tgN = *reinterpret_cast<const int4*>(conf_targets + (size_t)nt * 4);
    }
    __builtin_amdgcn_sched_barrier(0);
    COMPUTE(tile, tg0);
    tg0 = tg1; tg1 = tgN;
    tile += TOTAL_WAVES;
  }
#undef LOAD_DATA
#undef STAGE
#undef COMPUTE
}

// One block per batch row: fused positives+top-byte sweep, then 3 radix
// sweeps, then strictly-greater sum sweep (values L2-resident).
__global__ __launch_bounds__(1024) void mb_select(
    const float* __restrict__ mined, const float* __restrict__ loc_data,
    const float* __restrict__ loc_targets, float* __restrict__ partial,
    int* __restrict__ num_pos) {
  const int b = blockIdx.x;
  const float* __restrict__ row = mined + (size_t)b * NP;
  const int tid = threadIdx.x;
  const int wid = tid >> 6;
  const int lane = tid & 63;

  __shared__ int hist[16][256];
  __shared__ int total[256];
  __shared__ int suffix[256];
  __shared__ unsigned s_prefix;
  __shared__ int s_k;

  // ---- sweep 1: fused positives pre-pass + top-byte histogram ----
  for (int i = tid; i < 16 * 256; i += 1024) ((int*)hist)[i] = 0;
  __syncthreads();
  {
    int np = 0;
    float cp = 0.f, lv = 0.f;
    for (int q = tid; q < NP / 4; q += 1024) {
      const float4 v = reinterpret_cast<const float4*>(row)[q];
      const float vv[4] = {v.x, v.y, v.z, v.w};
#pragma unroll
      for (int j = 0; j < 4; ++j) {
        unsigned u = __float_as_uint(vv[j]);
        if (u >> 31) {
          np++;
          cp += -vv[j];
          const size_t flat = (size_t)b * NP + 4 * q + j;
          lv += smooth_l1_4(
              *reinterpret_cast<const float4*>(loc_data + flat * 4),
              *reinterpret_cast<const float4*>(loc_targets + flat * 4));
          u = 0u;
        }
        atomicAdd(&hist[wid][u >> 24], 1);
      }
    }
    __shared__ float rednp[16], redcp[16], redlv[16];
    float wnp = wave_reduce_sum((float)np);
    float wcp = wave_reduce_sum(cp);
    float wlv = wave_reduce_sum(lv);
    if (lane == 0) { rednp[wid] = wnp; redcp[wid] = wcp; redlv[wid] = wlv; }
    __syncthreads();
    if (tid == 0) {
      float tnp = 0.f, tcp = 0.f, tlv = 0.f;
#pragma unroll
      for (int i = 0; i < 16; ++i) { tnp += rednp[i]; tcp += redcp[i]; tlv += redlv[i]; }
      const int npi = (int)tnp;
      num_pos[b] = npi;
      partial[b * 4 + 0] = tlv;
      partial[b * 4 + 1] = tcp;
      int k = NEG_POS * npi;
      if (k > NP - 1) k = NP - 1;
      s_k = k;
      s_prefix = 0u;
    }
    __syncthreads();
  }

#define PASS_EPILOGUE(SHIFT)                                                  \
  do {                                                                        \
    if (tid < 256) {                                                          \
      int t = 0;                                                              \
      _Pragma("unroll")                                                       \
      for (int w = 0; w < 16; ++w) t += hist[w][tid];                         \
      total[tid] = t;                                                         \
    }                                                                         \
    __syncthreads();                                                          \
    if (wid == 0) {                                                           \
      const int t0_ = total[4 * lane + 0];                                    \
      const int t1_ = total[4 * lane + 1];                                    \
      const int t2_ = total[4 * lane + 2];                                    \
      const int t3_ = total[4 * lane + 3];                                    \
      const int s3 = t3_;                                                     \
      const int s2 = t2_ + s3;                                                \
      const int s1 = t1_ + s2;                                                \
      const int s0 = t0_ + s1;                                                \
      int acc_ = s0;                                                          \
      _Pragma("unroll")                                                       \
      for (int off = 1; off < 64; off <<= 1) {                                \
        const int o = __shfl_down(acc_, off, 64);                             \
        if (lane + off < 64) acc_ += o;                                       \
      }                                                                       \
      const int excl = acc_ - s0;                                             \
      suffix[4 * lane + 0] = s0 + excl;                                       \
      suffix[4 * lane + 1] = s1 + excl;                                       \
      suffix[4 * lane + 2] = s2 + excl;                                       \
      suffix[4 * lane + 3] = s3 + excl;                                       \
    }                                                                         \
    __syncthreads();                                                          \
    if (tid < 256) {                                                          \
      const int kcur = s_k;                                                   \
      const int cs = suffix[tid] - total[tid];                                \
      if (kcur >= cs && kcur < cs + total[tid]) {                             \
        s_prefix |= ((unsigned)tid << (SHIFT));                               \
        s_k = kcur - cs;                                                      \
      }                                                                       \
    }                                                                         \
    __syncthreads();                                                          \
  } while (0)

  PASS_EPILOGUE(24);

  for (int shift = 16; shift >= 0; shift -= 8) {
    for (int i = tid; i < 16 * 256; i += 1024) ((int*)hist)[i] = 0;
    __syncthreads();
    const unsigned mask = 0xFFFFFFFFu << (shift + 8);
    const unsigned pfx = s_prefix;

    for (int q = tid; q < NP / 4; q += 1024) {
      const float4 v = reinterpret_cast<const float4*>(row)[q];
      unsigned u;
      u = __float_as_uint(v.x); u = (u >> 31) ? 0u : u; if ((u & mask) == pfx) atomicAdd(&hist[wid][(u >> shift) & 255], 1);
      u = __float_as_uint(v.y); u = (u >> 31) ? 0u : u; if ((u & mask) == pfx) atomicAdd(&hist[wid][(u >> shift) & 255], 1);
      u = __float_as_uint(v.z); u = (u >> 31) ? 0u : u; if ((u & mask) == pfx) atomicAdd(&hist[wid][(u >> shift) & 255], 1);
      u = __float_as_uint(v.w); u = (u >> 31) ? 0u : u; if ((u & mask) == pfx) atomicAdd(&hist[wid][(u >> shift) & 255], 1);
    }
    __syncthreads();

    if (shift == 16) PASS_EPILOGUE(16);
    else if (shift == 8) PASS_EPILOGUE(8);
    else PASS_EPILOGUE(0);
  }
#undef PASS_EPILOGUE

  const unsigned vbits = s_prefix;
  float sum = 0.f;
  for (int q = tid; q < NP / 4; q += 1024) {
    const float4 v = reinterpret_cast<const float4*>(row)[q];
    unsigned u;
    u = __float_as_uint(v.x); u = (u >> 31) ? 0u : u; if (u > vbits) sum += v.x;
    u = __float_as_uint(v.y); u = (u >> 31) ? 0u : u; if (u > vbits) sum += v.y;
    u = __float_as_uint(v.z); u = (u >> 31) ? 0u : u; if (u > vbits) sum += v.z;
    u = __float_as_uint(v.w); u = (u >> 31) ? 0u : u; if (u > vbits) sum += v.w;
  }

  __shared__ float wsum[16];
  float w = wave_reduce_sum(sum);
  if (lane == 0) wsum[wid] = w;
  __syncthreads();
  if (tid == 0) {
    float t = 0.f;
#pragma unroll
    for (int i = 0; i < 16; ++i) t += wsum[i];
    partial[b * 4 + 2] = t;
  }
}

__global__ void mb_finalize(const float* __restrict__ partial,
                            const int* __restrict__ num_pos,
                            float* __restrict__ out) {
  if (threadIdx.x == 0) {
    double s = 0.0;
    int tot = 0;
#pragma unroll
    for (int i = 0; i < NB; ++i) {
      s += (double)partial[i * 4 + 0] + (double)partial[i * 4 + 1] +
           (double)partial[i * 4 + 2];
      tot += num_pos[i];
    }
    const double n = (double)(tot > 0 ? tot : 1);
    out[0] = (float)(s / n);
  }
}

extern "C" void kernel_launch(void* const* d_in, const int* in_sizes, int n_in,
                              void* d_out, int out_size, void* d_ws, size_t ws_size,
                              hipStream_t stream) {
  const float* loc_data     = (const float*)d_in[0];
  const float* conf_data    = (const float*)d_in[1];
  const float* loc_targets  = (const float*)d_in[2];
  const int*   conf_targets = (const int*)d_in[3];
  float* out = (float*)d_out;

  float* mined   = (float*)d_ws;
  float* partial = (float*)((char*)d_ws + MINED_BYTES);
  int*   num_pos = (int*)((char*)d_ws + MINED_BYTES + 512);

  mb_main<<<MAIN_BLOCKS, 256, 0, stream>>>(conf_data, conf_targets, mined);

  mb_select<<<NB, 1024, 0, stream>>>(mined, loc_data, loc_targets, partial, num_pos);

  mb_finalize<<<1, 64, 0, stream>>>(partial, num_pos, out);
}